// Round 1
// baseline (1223.544 us; speedup 1.0000x reference)
//
#include <hip/hip_runtime.h>
#include <math.h>

#define D_MODEL 512
#define D_FF    2048
#define NBATCH  2
#define NSEQ    384
#define NROWS   (NBATCH * NSEQ)
#define LN_EPS  1e-6f

// ---------------------------------------------------------------------------
// Kernel 1: x0[row,d] = emb[tokens[row], d] * sqrt(D) + PE(n, d)
// ---------------------------------------------------------------------------
__global__ __launch_bounds__(256) void embed_pe_kernel(
    const int* __restrict__ tokens, const float* __restrict__ emb,
    float* __restrict__ x)
{
    int row = blockIdx.x;            // b*NSEQ + n
    int n   = row % NSEQ;
    int tok = tokens[row];
    const float sqrtD = 22.627416997969522f; // sqrt(512)
    for (int d = threadIdx.x; d < D_MODEL; d += 256) {
        float e = emb[tok * D_MODEL + d] * sqrtD;
        int   i2   = d & ~1;
        float expo = (float)i2 / (float)D_MODEL;
        float ang  = (float)n * powf(10000.0f, -expo);
        float pe   = (d & 1) ? cosf(ang) : sinf(ang);
        x[row * D_MODEL + d] = e + pe;
    }
}

// ---------------------------------------------------------------------------
// Kernel 2: generic tiled fp32 GEMM: C[M,N] = A[M,K] @ W[K,N] + bias (+resid) (+relu)
// block = 256 threads (16x16), tile 64x64, each thread 4x4, BK=16
// M = gridDim.y*64 (all dims divisible)
// ---------------------------------------------------------------------------
#define BM 64
#define BN 64
#define BK 16
__global__ __launch_bounds__(256) void gemm_bias_kernel(
    const float* __restrict__ A, const float* __restrict__ W,
    const float* __restrict__ bias, const float* __restrict__ resid,
    float* __restrict__ C, int K, int N, int relu)
{
    __shared__ float As[BK][BM + 1];
    __shared__ float Bs[BK][BN + 1];

    int tid = threadIdx.x;
    int tx = tid & 15, ty = tid >> 4;
    int rowBase = blockIdx.y * BM;
    int colBase = blockIdx.x * BN;

    float acc[4][4] = {};

    for (int k0 = 0; k0 < K; k0 += BK) {
        // A tile: BM x BK
        #pragma unroll
        for (int i = tid; i < BM * BK; i += 256) {
            int r = i / BK, c = i % BK;
            As[c][r] = A[(size_t)(rowBase + r) * K + (k0 + c)];
        }
        // W tile: BK x BN
        #pragma unroll
        for (int i = tid; i < BK * BN; i += 256) {
            int r = i / BN, c = i % BN;
            Bs[r][c] = W[(size_t)(k0 + r) * N + (colBase + c)];
        }
        __syncthreads();
        #pragma unroll
        for (int kk = 0; kk < BK; ++kk) {
            float a[4], b[4];
            #pragma unroll
            for (int i = 0; i < 4; ++i) a[i] = As[kk][ty * 4 + i];
            #pragma unroll
            for (int j = 0; j < 4; ++j) b[j] = Bs[kk][tx * 4 + j];
            #pragma unroll
            for (int i = 0; i < 4; ++i)
                #pragma unroll
                for (int j = 0; j < 4; ++j)
                    acc[i][j] += a[i] * b[j];
        }
        __syncthreads();
    }

    #pragma unroll
    for (int i = 0; i < 4; ++i) {
        int r = rowBase + ty * 4 + i;
        #pragma unroll
        for (int j = 0; j < 4; ++j) {
            int c = colBase + tx * 4 + j;
            float val = acc[i][j] + bias[c];
            if (resid) val += resid[(size_t)r * N + c];
            if (relu)  val = fmaxf(val, 0.0f);
            C[(size_t)r * N + c] = val;
        }
    }
}

// ---------------------------------------------------------------------------
// Kernel 3: fused additive-attention scores + softmax + PV for one (b,i) row.
// block = 512 threads; blockIdx.x = b*NSEQ + i
// ---------------------------------------------------------------------------
__global__ __launch_bounds__(512) void attn_kernel(
    const float* __restrict__ q, const float* __restrict__ k,
    const float* __restrict__ v, const float* __restrict__ scale,
    float* __restrict__ out)
{
    int row = blockIdx.x;
    int b   = row / NSEQ;
    int tid = threadIdx.x;
    int lane = tid & 63, wid = tid >> 6;

    __shared__ float sc[NSEQ];
    __shared__ float red[8];

    // ---- phase 1: scores (threads 0..383, one j each)
    if (tid < NSEQ) {
        const float* qrow = q + (size_t)row * D_MODEL;
        const float* krow = k + (size_t)(b * NSEQ + tid) * D_MODEL;
        float s = 0.0f;
        for (int d = 0; d < D_MODEL; ++d)
            s += scale[d] * tanhf(qrow[d] + krow[d]);
        sc[tid] = s;
    }
    __syncthreads();

    // ---- softmax max
    float m = (tid < NSEQ) ? sc[tid] : -INFINITY;
    #pragma unroll
    for (int off = 32; off; off >>= 1) m = fmaxf(m, __shfl_xor(m, off, 64));
    if (lane == 0) red[wid] = m;
    __syncthreads();
    if (tid == 0) {
        float t = red[0];
        #pragma unroll
        for (int w = 1; w < 8; ++w) t = fmaxf(t, red[w]);
        red[0] = t;
    }
    __syncthreads();
    m = red[0];
    __syncthreads();

    // ---- exp + sum
    float e = 0.0f;
    if (tid < NSEQ) { e = expf(sc[tid] - m); }
    float s = e;
    #pragma unroll
    for (int off = 32; off; off >>= 1) s += __shfl_xor(s, off, 64);
    if (lane == 0) red[wid] = s;
    __syncthreads();
    if (tid == 0) {
        float t = 0.0f;
        #pragma unroll
        for (int w = 0; w < 8; ++w) t += red[w];
        red[0] = t;
    }
    __syncthreads();
    float inv = 1.0f / red[0];
    __syncthreads();
    if (tid < NSEQ) sc[tid] = e * inv;   // normalized weights
    __syncthreads();

    // ---- phase 2: out[row, d] = sum_j w[j] * v[b, j, d]; one d per thread
    const float* vb = v + (size_t)b * NSEQ * D_MODEL;
    float acc = 0.0f;
    for (int j = 0; j < NSEQ; ++j)
        acc += sc[j] * vb[(size_t)j * D_MODEL + tid];
    out[(size_t)row * D_MODEL + tid] = acc;
}

// ---------------------------------------------------------------------------
// Kernel 4: LayerNorm over last dim (512): out = (x-mu)/sqrt(var+eps)*g + b
// block = 256 threads, one row per block
// ---------------------------------------------------------------------------
__global__ __launch_bounds__(256) void ln_kernel(
    const float* __restrict__ in, const float* __restrict__ gamma,
    const float* __restrict__ beta, float* __restrict__ out)
{
    int row = blockIdx.x;
    int tid = threadIdx.x;
    int lane = tid & 63, wid = tid >> 6;
    __shared__ float red[4];

    float v0 = in[(size_t)row * D_MODEL + tid];
    float v1 = in[(size_t)row * D_MODEL + tid + 256];

    float s = v0 + v1;
    #pragma unroll
    for (int off = 32; off; off >>= 1) s += __shfl_xor(s, off, 64);
    if (lane == 0) red[wid] = s;
    __syncthreads();
    if (tid == 0) red[0] = red[0] + red[1] + red[2] + red[3];
    __syncthreads();
    float mu = red[0] * (1.0f / D_MODEL);
    __syncthreads();

    float d0 = v0 - mu, d1 = v1 - mu;
    float s2 = d0 * d0 + d1 * d1;
    #pragma unroll
    for (int off = 32; off; off >>= 1) s2 += __shfl_xor(s2, off, 64);
    if (lane == 0) red[wid] = s2;
    __syncthreads();
    if (tid == 0) red[0] = red[0] + red[1] + red[2] + red[3];
    __syncthreads();
    float var = red[0] * (1.0f / D_MODEL);
    float inv = rsqrtf(var + LN_EPS);

    out[(size_t)row * D_MODEL + tid]       = d0 * inv * gamma[tid] + beta[tid];
    out[(size_t)row * D_MODEL + tid + 256] = d1 * inv * gamma[tid + 256] + beta[tid + 256];
}

// ---------------------------------------------------------------------------
extern "C" void kernel_launch(void* const* d_in, const int* in_sizes, int n_in,
                              void* d_out, int out_size, void* d_ws, size_t ws_size,
                              hipStream_t stream)
{
    const int*   tokens = (const int*)  d_in[0];
    const float* emb    = (const float*)d_in[1];
    const float* Wq     = (const float*)d_in[2];
    const float* bq     = (const float*)d_in[3];
    const float* Wk     = (const float*)d_in[4];
    const float* bk     = (const float*)d_in[5];
    const float* Wv     = (const float*)d_in[6];
    const float* bv     = (const float*)d_in[7];
    const float* ascale = (const float*)d_in[8];
    const float* Wo     = (const float*)d_in[9];
    const float* bo     = (const float*)d_in[10];
    const float* g1     = (const float*)d_in[11];
    const float* beta1  = (const float*)d_in[12];
    const float* W1     = (const float*)d_in[13];
    const float* bf1    = (const float*)d_in[14];
    const float* W2     = (const float*)d_in[15];
    const float* bf2    = (const float*)d_in[16];
    const float* g2     = (const float*)d_in[17];
    const float* beta2  = (const float*)d_in[18];

    float* out = (float*)d_out;
    float* ws  = (float*)d_ws;

    float* x0   = ws;                       // NROWS * D_MODEL
    float* q    = x0   + (size_t)NROWS * D_MODEL;
    float* k    = q    + (size_t)NROWS * D_MODEL;
    float* v    = k    + (size_t)NROWS * D_MODEL;
    float* attn = v    + (size_t)NROWS * D_MODEL;
    float* t1   = attn + (size_t)NROWS * D_MODEL;
    float* x1   = t1   + (size_t)NROWS * D_MODEL;
    float* h    = x1   + (size_t)NROWS * D_MODEL;   // NROWS * D_FF
    float* y    = h    + (size_t)NROWS * D_FF;

    // 1. embedding + positional encoding
    embed_pe_kernel<<<NROWS, 256, 0, stream>>>(tokens, emb, x0);

    // 2-4. q, k, v projections
    dim3 gD(D_MODEL / BN, NROWS / BM);
    gemm_bias_kernel<<<gD, 256, 0, stream>>>(x0, Wq, bq, nullptr, q, D_MODEL, D_MODEL, 0);
    gemm_bias_kernel<<<gD, 256, 0, stream>>>(x0, Wk, bk, nullptr, k, D_MODEL, D_MODEL, 0);
    gemm_bias_kernel<<<gD, 256, 0, stream>>>(x0, Wv, bv, nullptr, v, D_MODEL, D_MODEL, 0);

    // 5. additive attention (scores + softmax + PV)
    attn_kernel<<<NROWS, 512, 0, stream>>>(q, k, v, ascale, attn);

    // 6. output projection + residual
    gemm_bias_kernel<<<gD, 256, 0, stream>>>(attn, Wo, bo, x0, t1, D_MODEL, D_MODEL, 0);

    // 7. LayerNorm 1
    ln_kernel<<<NROWS, 256, 0, stream>>>(t1, g1, beta1, x1);

    // 8. FF up + ReLU
    dim3 gF(D_FF / BN, NROWS / BM);
    gemm_bias_kernel<<<gF, 256, 0, stream>>>(x1, W1, bf1, nullptr, h, D_MODEL, D_FF, 1);

    // 9. FF down + residual
    gemm_bias_kernel<<<gD, 256, 0, stream>>>(h, W2, bf2, x1, y, D_FF, D_MODEL, 0);

    // 10. LayerNorm 2 -> out
    ln_kernel<<<NROWS, 256, 0, stream>>>(y, g2, beta2, out);
}

// Round 2
// 646.724 us; speedup vs baseline: 1.8919x; 1.8919x over previous
//
#include <hip/hip_runtime.h>
#include <math.h>

#define D_MODEL 512
#define D_FF    2048
#define NBATCH  2
#define NSEQ    384
#define NROWS   (NBATCH * NSEQ)
#define LN_EPS  1e-6f

// ---------------------------------------------------------------------------
// fast tanh: 1 - 2/(exp(2x)+1), native exp + native rcp.
// Saturates correctly: x>>0 -> e=inf -> 1; x<<0 -> e=0 -> -1.
// ---------------------------------------------------------------------------
__device__ __forceinline__ float fast_tanh(float x) {
    float e = __expf(2.0f * x);
    return 1.0f - 2.0f * __builtin_amdgcn_rcpf(e + 1.0f);
}

// ---------------------------------------------------------------------------
// Kernel 1: x0[row,d] = emb[tokens[row], d] * sqrt(D) + PE(n, d)
// ---------------------------------------------------------------------------
__global__ __launch_bounds__(256) void embed_pe_kernel(
    const int* __restrict__ tokens, const float* __restrict__ emb,
    float* __restrict__ x)
{
    int row = blockIdx.x;            // b*NSEQ + n
    int n   = row % NSEQ;
    int tok = tokens[row];
    const float sqrtD = 22.627416997969522f; // sqrt(512)
    for (int d = threadIdx.x; d < D_MODEL; d += 256) {
        float e = emb[tok * D_MODEL + d] * sqrtD;
        int   i2   = d & ~1;
        float expo = (float)i2 / (float)D_MODEL;
        float ang  = (float)n * powf(10000.0f, -expo);
        float pe   = (d & 1) ? cosf(ang) : sinf(ang);
        x[row * D_MODEL + d] = e + pe;
    }
}

// ---------------------------------------------------------------------------
// Kernel 2: tiled fp32 GEMM: C[M,N] = A[M,K] @ W[K,N] + bias (+resid) (+relu)
// block = 256 threads (16x16), tile 32x64, each thread 2x4, BK=16
// ---------------------------------------------------------------------------
#define BM 32
#define BN 64
#define BK 16
__global__ __launch_bounds__(256) void gemm_bias_kernel(
    const float* __restrict__ A, const float* __restrict__ W,
    const float* __restrict__ bias, const float* __restrict__ resid,
    float* __restrict__ C, int K, int N, int relu)
{
    __shared__ float As[BK][BM + 1];
    __shared__ float Bs[BK][BN + 1];

    int tid = threadIdx.x;
    int tx = tid & 15, ty = tid >> 4;
    int rowBase = blockIdx.y * BM;
    int colBase = blockIdx.x * BN;

    float acc[2][4] = {};

    for (int k0 = 0; k0 < K; k0 += BK) {
        // A tile: BM x BK  (512 elements, 2 per thread)
        #pragma unroll
        for (int i = tid; i < BM * BK; i += 256) {
            int r = i / BK, c = i % BK;
            As[c][r] = A[(size_t)(rowBase + r) * K + (k0 + c)];
        }
        // W tile: BK x BN  (1024 elements, 4 per thread)
        #pragma unroll
        for (int i = tid; i < BK * BN; i += 256) {
            int r = i / BN, c = i % BN;
            Bs[r][c] = W[(size_t)(k0 + r) * N + (colBase + c)];
        }
        __syncthreads();
        #pragma unroll
        for (int kk = 0; kk < BK; ++kk) {
            float a[2], b[4];
            #pragma unroll
            for (int i = 0; i < 2; ++i) a[i] = As[kk][ty * 2 + i];
            #pragma unroll
            for (int j = 0; j < 4; ++j) b[j] = Bs[kk][tx * 4 + j];
            #pragma unroll
            for (int i = 0; i < 2; ++i)
                #pragma unroll
                for (int j = 0; j < 4; ++j)
                    acc[i][j] += a[i] * b[j];
        }
        __syncthreads();
    }

    #pragma unroll
    for (int i = 0; i < 2; ++i) {
        int r = rowBase + ty * 2 + i;
        #pragma unroll
        for (int j = 0; j < 4; ++j) {
            int c = colBase + tx * 4 + j;
            float val = acc[i][j] + bias[c];
            if (resid) val += resid[(size_t)r * N + c];
            if (relu)  val = fmaxf(val, 0.0f);
            C[(size_t)r * N + c] = val;
        }
    }
}

// ---------------------------------------------------------------------------
// Kernel 3: fused additive-attention scores + softmax + PV for one (b,i) row.
// block = 512 threads (8 waves); blockIdx.x = b*NSEQ + i
// Phase 1: wave w handles score rows j = w, w+8, ...; lane l owns d-slice
//          [8l, 8l+8) -> coalesced float4 k loads, wave shfl_xor reduce.
// ---------------------------------------------------------------------------
__global__ __launch_bounds__(512) void attn_kernel(
    const float* __restrict__ q, const float* __restrict__ k,
    const float* __restrict__ v, const float* __restrict__ scale,
    float* __restrict__ out)
{
    int row = blockIdx.x;
    int b   = row / NSEQ;
    int tid = threadIdx.x;
    int lane = tid & 63, wid = tid >> 6;

    __shared__ float qs[D_MODEL];
    __shared__ float ss[D_MODEL];
    __shared__ float sc[NSEQ];
    __shared__ float red[8];

    qs[tid] = q[(size_t)row * D_MODEL + tid];
    ss[tid] = scale[tid];
    __syncthreads();

    // per-lane fragments of q and scale (d = lane*8 + u)
    float qv[8], sv[8];
    #pragma unroll
    for (int u = 0; u < 8; ++u) {
        qv[u] = qs[lane * 8 + u];
        sv[u] = ss[lane * 8 + u];
    }

    // ---- phase 1: scores
    const float* kb = k + (size_t)b * NSEQ * D_MODEL + lane * 8;
    for (int j = wid; j < NSEQ; j += 8) {
        const float4* kp = (const float4*)(kb + (size_t)j * D_MODEL);
        float4 k0 = kp[0], k1 = kp[1];
        float acc;
        acc  = sv[0] * fast_tanh(qv[0] + k0.x);
        acc += sv[1] * fast_tanh(qv[1] + k0.y);
        acc += sv[2] * fast_tanh(qv[2] + k0.z);
        acc += sv[3] * fast_tanh(qv[3] + k0.w);
        acc += sv[4] * fast_tanh(qv[4] + k1.x);
        acc += sv[5] * fast_tanh(qv[5] + k1.y);
        acc += sv[6] * fast_tanh(qv[6] + k1.z);
        acc += sv[7] * fast_tanh(qv[7] + k1.w);
        #pragma unroll
        for (int off = 32; off; off >>= 1) acc += __shfl_xor(acc, off, 64);
        if (lane == 0) sc[j] = acc;
    }
    __syncthreads();

    // ---- softmax max
    float m = (tid < NSEQ) ? sc[tid] : -INFINITY;
    #pragma unroll
    for (int off = 32; off; off >>= 1) m = fmaxf(m, __shfl_xor(m, off, 64));
    if (lane == 0) red[wid] = m;
    __syncthreads();
    if (tid == 0) {
        float t = red[0];
        #pragma unroll
        for (int w = 1; w < 8; ++w) t = fmaxf(t, red[w]);
        red[0] = t;
    }
    __syncthreads();
    m = red[0];
    __syncthreads();

    // ---- exp + sum
    float e = 0.0f;
    if (tid < NSEQ) e = __expf(sc[tid] - m);
    float s = e;
    #pragma unroll
    for (int off = 32; off; off >>= 1) s += __shfl_xor(s, off, 64);
    if (lane == 0) red[wid] = s;
    __syncthreads();
    if (tid == 0) {
        float t = 0.0f;
        #pragma unroll
        for (int w = 0; w < 8; ++w) t += red[w];
        red[0] = t;
    }
    __syncthreads();
    float inv = 1.0f / red[0];
    __syncthreads();
    if (tid < NSEQ) sc[tid] = e * inv;   // normalized weights
    __syncthreads();

    // ---- phase 2: out[row, d] = sum_j w[j] * v[b, j, d]; one d per thread
    const float* vb = v + (size_t)b * NSEQ * D_MODEL + tid;
    float acc = 0.0f;
    #pragma unroll 4
    for (int j = 0; j < NSEQ; ++j)
        acc += sc[j] * vb[(size_t)j * D_MODEL];
    out[(size_t)row * D_MODEL + tid] = acc;
}

// ---------------------------------------------------------------------------
// Kernel 4: LayerNorm over last dim (512)
// ---------------------------------------------------------------------------
__global__ __launch_bounds__(256) void ln_kernel(
    const float* __restrict__ in, const float* __restrict__ gamma,
    const float* __restrict__ beta, float* __restrict__ out)
{
    int row = blockIdx.x;
    int tid = threadIdx.x;
    int lane = tid & 63, wid = tid >> 6;
    __shared__ float red[4];

    float v0 = in[(size_t)row * D_MODEL + tid];
    float v1 = in[(size_t)row * D_MODEL + tid + 256];

    float s = v0 + v1;
    #pragma unroll
    for (int off = 32; off; off >>= 1) s += __shfl_xor(s, off, 64);
    if (lane == 0) red[wid] = s;
    __syncthreads();
    if (tid == 0) red[0] = red[0] + red[1] + red[2] + red[3];
    __syncthreads();
    float mu = red[0] * (1.0f / D_MODEL);
    __syncthreads();

    float d0 = v0 - mu, d1 = v1 - mu;
    float s2 = d0 * d0 + d1 * d1;
    #pragma unroll
    for (int off = 32; off; off >>= 1) s2 += __shfl_xor(s2, off, 64);
    if (lane == 0) red[wid] = s2;
    __syncthreads();
    if (tid == 0) red[0] = red[0] + red[1] + red[2] + red[3];
    __syncthreads();
    float var = red[0] * (1.0f / D_MODEL);
    float inv = rsqrtf(var + LN_EPS);

    out[(size_t)row * D_MODEL + tid]       = d0 * inv * gamma[tid] + beta[tid];
    out[(size_t)row * D_MODEL + tid + 256] = d1 * inv * gamma[tid + 256] + beta[tid + 256];
}

// ---------------------------------------------------------------------------
extern "C" void kernel_launch(void* const* d_in, const int* in_sizes, int n_in,
                              void* d_out, int out_size, void* d_ws, size_t ws_size,
                              hipStream_t stream)
{
    const int*   tokens = (const int*)  d_in[0];
    const float* emb    = (const float*)d_in[1];
    const float* Wq     = (const float*)d_in[2];
    const float* bq     = (const float*)d_in[3];
    const float* Wk     = (const float*)d_in[4];
    const float* bk     = (const float*)d_in[5];
    const float* Wv     = (const float*)d_in[6];
    const float* bv     = (const float*)d_in[7];
    const float* ascale = (const float*)d_in[8];
    const float* Wo     = (const float*)d_in[9];
    const float* bo     = (const float*)d_in[10];
    const float* g1     = (const float*)d_in[11];
    const float* beta1  = (const float*)d_in[12];
    const float* W1     = (const float*)d_in[13];
    const float* bf1    = (const float*)d_in[14];
    const float* W2     = (const float*)d_in[15];
    const float* bf2    = (const float*)d_in[16];
    const float* g2     = (const float*)d_in[17];
    const float* beta2  = (const float*)d_in[18];

    float* out = (float*)d_out;
    float* ws  = (float*)d_ws;

    float* x0   = ws;                       // NROWS * D_MODEL
    float* q    = x0   + (size_t)NROWS * D_MODEL;
    float* k    = q    + (size_t)NROWS * D_MODEL;
    float* v    = k    + (size_t)NROWS * D_MODEL;
    float* attn = v    + (size_t)NROWS * D_MODEL;
    float* t1   = attn + (size_t)NROWS * D_MODEL;
    float* x1   = t1   + (size_t)NROWS * D_MODEL;
    float* h    = x1   + (size_t)NROWS * D_MODEL;   // NROWS * D_FF
    float* y    = h    + (size_t)NROWS * D_FF;

    // 1. embedding + positional encoding
    embed_pe_kernel<<<NROWS, 256, 0, stream>>>(tokens, emb, x0);

    // 2-4. q, k, v projections
    dim3 gD(D_MODEL / BN, NROWS / BM);
    gemm_bias_kernel<<<gD, 256, 0, stream>>>(x0, Wq, bq, nullptr, q, D_MODEL, D_MODEL, 0);
    gemm_bias_kernel<<<gD, 256, 0, stream>>>(x0, Wk, bk, nullptr, k, D_MODEL, D_MODEL, 0);
    gemm_bias_kernel<<<gD, 256, 0, stream>>>(x0, Wv, bv, nullptr, v, D_MODEL, D_MODEL, 0);

    // 5. additive attention (scores + softmax + PV)
    attn_kernel<<<NROWS, 512, 0, stream>>>(q, k, v, ascale, attn);

    // 6. output projection + residual
    gemm_bias_kernel<<<gD, 256, 0, stream>>>(attn, Wo, bo, x0, t1, D_MODEL, D_MODEL, 0);

    // 7. LayerNorm 1
    ln_kernel<<<NROWS, 256, 0, stream>>>(t1, g1, beta1, x1);

    // 8. FF up + ReLU
    dim3 gF(D_FF / BN, NROWS / BM);
    gemm_bias_kernel<<<gF, 256, 0, stream>>>(x1, W1, bf1, nullptr, h, D_MODEL, D_FF, 1);

    // 9. FF down + residual
    gemm_bias_kernel<<<gD, 256, 0, stream>>>(h, W2, bf2, x1, y, D_FF, D_MODEL, 0);

    // 10. LayerNorm 2 -> out
    ln_kernel<<<NROWS, 256, 0, stream>>>(y, g2, beta2, out);
}

// Round 3
// 180.713 us; speedup vs baseline: 6.7707x; 3.5787x over previous
//
#include <hip/hip_runtime.h>
#include <hip/hip_bf16.h>
#include <math.h>

#define D_MODEL 512
#define D_FF    2048
#define NBATCH  2
#define NSEQ    384
#define NROWS   (NBATCH * NSEQ)
#define LN_EPS  1e-6f

typedef __attribute__((ext_vector_type(8))) short short8;
typedef __attribute__((ext_vector_type(4))) float f32x4;
typedef __hip_bfloat16 bf16;

// ---------------------------------------------------------------------------
// fast tanh: 1 - 2/(exp(2x)+1); saturates correctly at +-inf.
// ---------------------------------------------------------------------------
__device__ __forceinline__ float fast_tanh(float x) {
    float e = __expf(2.0f * x);
    return 1.0f - 2.0f * __builtin_amdgcn_rcpf(e + 1.0f);
}

// ---------------------------------------------------------------------------
// Kernel 1: x0[row,d] = emb[tokens[row], d]*sqrt(D) + PE(n,d); f32 + bf16 copy
// ---------------------------------------------------------------------------
__global__ __launch_bounds__(256) void embed_pe_kernel(
    const int* __restrict__ tokens, const float* __restrict__ emb,
    float* __restrict__ x, bf16* __restrict__ xb)
{
    int row = blockIdx.x;            // b*NSEQ + n
    int n   = row % NSEQ;
    int tok = tokens[row];
    const float sqrtD = 22.627416997969522f; // sqrt(512)
    for (int d = threadIdx.x; d < D_MODEL; d += 256) {
        float e = emb[tok * D_MODEL + d] * sqrtD;
        int   i2   = d & ~1;
        float expo = (float)i2 / (float)D_MODEL;
        float ang  = (float)n * powf(10000.0f, -expo);
        float pe   = (d & 1) ? cosf(ang) : sinf(ang);
        float val  = e + pe;
        x [(size_t)row * D_MODEL + d] = val;
        xb[(size_t)row * D_MODEL + d] = __float2bfloat16(val);
    }
}

// ---------------------------------------------------------------------------
// Kernel 2: weight convert + transpose: W[K][N] f32 -> Wt[N][K] bf16
// grid (N/32, K/32), 256 threads
// ---------------------------------------------------------------------------
__global__ __launch_bounds__(256) void wt_bf16_kernel(
    const float* __restrict__ W, bf16* __restrict__ Wt, int K, int N)
{
    __shared__ float tile[32][33];
    int bx = blockIdx.x, by = blockIdx.y;
    int tx = threadIdx.x & 31, ty = threadIdx.x >> 5; // ty: 0..7
    #pragma unroll
    for (int r = ty; r < 32; r += 8)
        tile[r][tx] = W[(size_t)(by * 32 + r) * N + bx * 32 + tx];
    __syncthreads();
    #pragma unroll
    for (int r = ty; r < 32; r += 8)
        Wt[(size_t)(bx * 32 + r) * K + by * 32 + tx] = __float2bfloat16(tile[tx][r]);
}

// ---------------------------------------------------------------------------
// Kernel 3: bf16 MFMA GEMM, no LDS. C[M,N] = A[M,K] @ Wt[N,K]^T + bias
// (+resid) (+relu). Block 256 thr = 4 waves; tile 32x64; wave = 16x32.
// gridDim.z selects among (Wt0,bias0,C0)/(1)/(2) for fused QKV.
// ---------------------------------------------------------------------------
__global__ __launch_bounds__(256) void mfma_gemm_kernel(
    const bf16* __restrict__ A,
    const bf16* __restrict__ Wt0, const bf16* __restrict__ Wt1, const bf16* __restrict__ Wt2,
    const float* __restrict__ bias0, const float* __restrict__ bias1, const float* __restrict__ bias2,
    const float* __restrict__ resid,
    float* __restrict__ C0, float* __restrict__ C1, float* __restrict__ C2,
    bf16* __restrict__ Cb,
    int K, int N, int relu)
{
    int z = blockIdx.z;
    const bf16*  Wt   = (z == 0) ? Wt0   : (z == 1) ? Wt1   : Wt2;
    const float* bias = (z == 0) ? bias0 : (z == 1) ? bias1 : bias2;
    float*       Cf   = (z == 0) ? C0    : (z == 1) ? C1    : C2;

    int lane = threadIdx.x & 63, wid = threadIdx.x >> 6;
    int rowBase = blockIdx.y * 32 + (wid >> 1) * 16;
    int colBase = blockIdx.x * 64 + (wid & 1) * 32;

    const bf16* Ap  = A  + (size_t)(rowBase + (lane & 15)) * K + ((lane >> 4) << 3);
    const bf16* Bp0 = Wt + (size_t)(colBase + (lane & 15)) * K + ((lane >> 4) << 3);
    const bf16* Bp1 = Bp0 + (size_t)16 * K;

    f32x4 acc0 = {0.f, 0.f, 0.f, 0.f};
    f32x4 acc1 = {0.f, 0.f, 0.f, 0.f};

    #pragma unroll 4
    for (int k0 = 0; k0 < K; k0 += 32) {
        short8 a  = *reinterpret_cast<const short8*>(Ap  + k0);
        short8 b0 = *reinterpret_cast<const short8*>(Bp0 + k0);
        short8 b1 = *reinterpret_cast<const short8*>(Bp1 + k0);
        acc0 = __builtin_amdgcn_mfma_f32_16x16x32_bf16(a, b0, acc0, 0, 0, 0);
        acc1 = __builtin_amdgcn_mfma_f32_16x16x32_bf16(a, b1, acc1, 0, 0, 0);
    }

    // C/D layout (m89): col = lane&15, row = (lane>>4)*4 + reg
    int crow = rowBase + ((lane >> 4) << 2);
    int ccol = colBase + (lane & 15);
    #pragma unroll
    for (int r = 0; r < 4; ++r) {
        int row = crow + r;
        #pragma unroll
        for (int j = 0; j < 2; ++j) {
            int col = ccol + j * 16;
            float val = (j == 0 ? acc0[r] : acc1[r]) + bias[col];
            if (resid) val += resid[(size_t)row * N + col];
            if (relu)  val = fmaxf(val, 0.0f);
            if (Cf) Cf[(size_t)row * N + col] = val;
            if (Cb) Cb[(size_t)row * N + col] = __float2bfloat16(val);
        }
    }
}

// ---------------------------------------------------------------------------
// Kernel 4: fused additive-attention scores + softmax + PV for one (b,i) row.
// ---------------------------------------------------------------------------
__global__ __launch_bounds__(512) void attn_kernel(
    const float* __restrict__ q, const float* __restrict__ k,
    const float* __restrict__ v, const float* __restrict__ scale,
    float* __restrict__ out, bf16* __restrict__ outb)
{
    int row = blockIdx.x;
    int b   = row / NSEQ;
    int tid = threadIdx.x;
    int lane = tid & 63, wid = tid >> 6;

    __shared__ float qs[D_MODEL];
    __shared__ float ss[D_MODEL];
    __shared__ float sc[NSEQ];
    __shared__ float red[8];

    qs[tid] = q[(size_t)row * D_MODEL + tid];
    ss[tid] = scale[tid];
    __syncthreads();

    float qv[8], sv[8];
    #pragma unroll
    for (int u = 0; u < 8; ++u) {
        qv[u] = qs[lane * 8 + u];
        sv[u] = ss[lane * 8 + u];
    }

    // ---- phase 1: scores
    const float* kb = k + (size_t)b * NSEQ * D_MODEL + lane * 8;
    for (int j = wid; j < NSEQ; j += 8) {
        const float4* kp = (const float4*)(kb + (size_t)j * D_MODEL);
        float4 k0 = kp[0], k1 = kp[1];
        float acc;
        acc  = sv[0] * fast_tanh(qv[0] + k0.x);
        acc += sv[1] * fast_tanh(qv[1] + k0.y);
        acc += sv[2] * fast_tanh(qv[2] + k0.z);
        acc += sv[3] * fast_tanh(qv[3] + k0.w);
        acc += sv[4] * fast_tanh(qv[4] + k1.x);
        acc += sv[5] * fast_tanh(qv[5] + k1.y);
        acc += sv[6] * fast_tanh(qv[6] + k1.z);
        acc += sv[7] * fast_tanh(qv[7] + k1.w);
        #pragma unroll
        for (int off = 32; off; off >>= 1) acc += __shfl_xor(acc, off, 64);
        if (lane == 0) sc[j] = acc;
    }
    __syncthreads();

    // ---- softmax max
    float m = (tid < NSEQ) ? sc[tid] : -INFINITY;
    #pragma unroll
    for (int off = 32; off; off >>= 1) m = fmaxf(m, __shfl_xor(m, off, 64));
    if (lane == 0) red[wid] = m;
    __syncthreads();
    if (tid == 0) {
        float t = red[0];
        #pragma unroll
        for (int w = 1; w < 8; ++w) t = fmaxf(t, red[w]);
        red[0] = t;
    }
    __syncthreads();
    m = red[0];
    __syncthreads();

    // ---- exp + sum
    float e = 0.0f;
    if (tid < NSEQ) e = __expf(sc[tid] - m);
    float s = e;
    #pragma unroll
    for (int off = 32; off; off >>= 1) s += __shfl_xor(s, off, 64);
    if (lane == 0) red[wid] = s;
    __syncthreads();
    if (tid == 0) {
        float t = 0.0f;
        #pragma unroll
        for (int w = 0; w < 8; ++w) t += red[w];
        red[0] = t;
    }
    __syncthreads();
    float inv = 1.0f / red[0];
    __syncthreads();
    if (tid < NSEQ) sc[tid] = e * inv;
    __syncthreads();

    // ---- phase 2: out[row, d] = sum_j w[j] * v[b, j, d]
    const float* vb = v + (size_t)b * NSEQ * D_MODEL + tid;
    float acc = 0.0f;
    #pragma unroll 4
    for (int j = 0; j < NSEQ; ++j)
        acc += sc[j] * vb[(size_t)j * D_MODEL];
    out [(size_t)row * D_MODEL + tid] = acc;
    outb[(size_t)row * D_MODEL + tid] = __float2bfloat16(acc);
}

// ---------------------------------------------------------------------------
// Kernel 5: LayerNorm over last dim (512); optional bf16 shadow output
// ---------------------------------------------------------------------------
__global__ __launch_bounds__(256) void ln_kernel(
    const float* __restrict__ in, const float* __restrict__ gamma,
    const float* __restrict__ beta, float* __restrict__ out,
    bf16* __restrict__ outb)
{
    int row = blockIdx.x;
    int tid = threadIdx.x;
    int lane = tid & 63, wid = tid >> 6;
    __shared__ float red[4];

    float v0 = in[(size_t)row * D_MODEL + tid];
    float v1 = in[(size_t)row * D_MODEL + tid + 256];

    float s = v0 + v1;
    #pragma unroll
    for (int off = 32; off; off >>= 1) s += __shfl_xor(s, off, 64);
    if (lane == 0) red[wid] = s;
    __syncthreads();
    if (tid == 0) red[0] = red[0] + red[1] + red[2] + red[3];
    __syncthreads();
    float mu = red[0] * (1.0f / D_MODEL);
    __syncthreads();

    float d0 = v0 - mu, d1 = v1 - mu;
    float s2 = d0 * d0 + d1 * d1;
    #pragma unroll
    for (int off = 32; off; off >>= 1) s2 += __shfl_xor(s2, off, 64);
    if (lane == 0) red[wid] = s2;
    __syncthreads();
    if (tid == 0) red[0] = red[0] + red[1] + red[2] + red[3];
    __syncthreads();
    float var = red[0] * (1.0f / D_MODEL);
    float inv = rsqrtf(var + LN_EPS);

    float o0 = d0 * inv * gamma[tid] + beta[tid];
    float o1 = d1 * inv * gamma[tid + 256] + beta[tid + 256];
    out[(size_t)row * D_MODEL + tid]       = o0;
    out[(size_t)row * D_MODEL + tid + 256] = o1;
    if (outb) {
        outb[(size_t)row * D_MODEL + tid]       = __float2bfloat16(o0);
        outb[(size_t)row * D_MODEL + tid + 256] = __float2bfloat16(o1);
    }
}

// ---------------------------------------------------------------------------
extern "C" void kernel_launch(void* const* d_in, const int* in_sizes, int n_in,
                              void* d_out, int out_size, void* d_ws, size_t ws_size,
                              hipStream_t stream)
{
    const int*   tokens = (const int*)  d_in[0];
    const float* emb    = (const float*)d_in[1];
    const float* Wq     = (const float*)d_in[2];
    const float* bq     = (const float*)d_in[3];
    const float* Wk     = (const float*)d_in[4];
    const float* bk     = (const float*)d_in[5];
    const float* Wv     = (const float*)d_in[6];
    const float* bv     = (const float*)d_in[7];
    const float* ascale = (const float*)d_in[8];
    const float* Wo     = (const float*)d_in[9];
    const float* bo     = (const float*)d_in[10];
    const float* g1     = (const float*)d_in[11];
    const float* beta1  = (const float*)d_in[12];
    const float* W1     = (const float*)d_in[13];
    const float* bf1    = (const float*)d_in[14];
    const float* W2     = (const float*)d_in[15];
    const float* bf2    = (const float*)d_in[16];
    const float* g2     = (const float*)d_in[17];
    const float* beta2  = (const float*)d_in[18];

    float* out = (float*)d_out;
    float* ws  = (float*)d_ws;

    const size_t SZ = (size_t)NROWS * D_MODEL;   // 393216

    float* x0    = ws;
    float* q     = ws + 1 * SZ;
    float* k     = ws + 2 * SZ;
    float* v     = ws + 3 * SZ;
    float* attnf = ws + 4 * SZ;
    float* t1 = q;   // q dead after attn
    float* x1 = k;   // k dead after attn
    float* y  = v;   // v dead after attn

    bf16* x0b   = (bf16*)(ws + 5 * SZ);
    bf16* attnb = x0b + SZ;
    bf16* x1b   = attnb + SZ;
    bf16* hb    = x1b + SZ;                         // NROWS * D_FF
    bf16* wqt   = hb + (size_t)NROWS * D_FF;
    bf16* wkt   = wqt + (size_t)D_MODEL * D_MODEL;
    bf16* wvt   = wkt + (size_t)D_MODEL * D_MODEL;
    bf16* wot   = wvt + (size_t)D_MODEL * D_MODEL;
    bf16* w1t   = wot + (size_t)D_MODEL * D_MODEL;  // D_FF x D_MODEL
    bf16* w2t   = w1t + (size_t)D_MODEL * D_FF;     // D_MODEL x D_FF

    // 0. weight convert+transpose (bf16, [N][K])
    wt_bf16_kernel<<<dim3(D_MODEL/32, D_MODEL/32), 256, 0, stream>>>(Wq, wqt, D_MODEL, D_MODEL);
    wt_bf16_kernel<<<dim3(D_MODEL/32, D_MODEL/32), 256, 0, stream>>>(Wk, wkt, D_MODEL, D_MODEL);
    wt_bf16_kernel<<<dim3(D_MODEL/32, D_MODEL/32), 256, 0, stream>>>(Wv, wvt, D_MODEL, D_MODEL);
    wt_bf16_kernel<<<dim3(D_MODEL/32, D_MODEL/32), 256, 0, stream>>>(Wo, wot, D_MODEL, D_MODEL);
    wt_bf16_kernel<<<dim3(D_FF/32,    D_MODEL/32), 256, 0, stream>>>(W1, w1t, D_MODEL, D_FF);
    wt_bf16_kernel<<<dim3(D_MODEL/32, D_FF/32),    256, 0, stream>>>(W2, w2t, D_FF, D_MODEL);

    // 1. embedding + positional encoding
    embed_pe_kernel<<<NROWS, 256, 0, stream>>>(tokens, emb, x0, x0b);

    // 2. fused QKV projections (gridDim.z = 3)
    mfma_gemm_kernel<<<dim3(D_MODEL/64, NROWS/32, 3), 256, 0, stream>>>(
        x0b, wqt, wkt, wvt, bq, bk, bv, nullptr, q, k, v, nullptr, D_MODEL, D_MODEL, 0);

    // 3. additive attention
    attn_kernel<<<NROWS, 512, 0, stream>>>(q, k, v, ascale, attnf, attnb);

    // 4. output projection + residual
    mfma_gemm_kernel<<<dim3(D_MODEL/64, NROWS/32, 1), 256, 0, stream>>>(
        attnb, wot, wot, wot, bo, bo, bo, x0, t1, t1, t1, nullptr, D_MODEL, D_MODEL, 0);

    // 5. LayerNorm 1 (f32 + bf16)
    ln_kernel<<<NROWS, 256, 0, stream>>>(t1, g1, beta1, x1, x1b);

    // 6. FF up + ReLU -> bf16 h only
    mfma_gemm_kernel<<<dim3(D_FF/64, NROWS/32, 1), 256, 0, stream>>>(
        x1b, w1t, w1t, w1t, bf1, bf1, bf1, nullptr,
        nullptr, nullptr, nullptr, hb, D_MODEL, D_FF, 1);

    // 7. FF down + residual
    mfma_gemm_kernel<<<dim3(D_MODEL/64, NROWS/32, 1), 256, 0, stream>>>(
        hb, w2t, w2t, w2t, bf2, bf2, bf2, x1, y, y, y, nullptr, D_FF, D_MODEL, 0);

    // 8. LayerNorm 2 -> out
    ln_kernel<<<NROWS, 256, 0, stream>>>(y, g2, beta2, out, nullptr);
}

// Round 4
// 138.392 us; speedup vs baseline: 8.8412x; 1.3058x over previous
//
#include <hip/hip_runtime.h>
#include <hip/hip_bf16.h>
#include <math.h>

#define D_MODEL 512
#define D_FF    2048
#define NBATCH  2
#define NSEQ    384
#define NROWS   (NBATCH * NSEQ)
#define LN_EPS  1e-6f

typedef __attribute__((ext_vector_type(8))) short short8;
typedef __attribute__((ext_vector_type(4))) short short4v;
typedef __attribute__((ext_vector_type(4))) float f32x4;
typedef __hip_bfloat16 bf16;

static __device__ __forceinline__ short bfb(float x) {
    bf16 h = __float2bfloat16(x);
    return *reinterpret_cast<short*>(&h);
}

// ---------------------------------------------------------------------------
// Kernel 1: all six weight transposes fused. W[K][N] f32 -> Wt[N][K] bf16.
// flat grid of 3072 32x32 tiles.
// ---------------------------------------------------------------------------
__global__ __launch_bounds__(256) void wt_all_kernel(
    const float* __restrict__ Wq, const float* __restrict__ Wk,
    const float* __restrict__ Wv, const float* __restrict__ Wo,
    const float* __restrict__ W1, const float* __restrict__ W2,
    bf16* __restrict__ wqt, bf16* __restrict__ wkt, bf16* __restrict__ wvt,
    bf16* __restrict__ wot, bf16* __restrict__ w1t, bf16* __restrict__ w2t)
{
    int t = blockIdx.x;
    const float* W; bf16* Wt; int K, N, bx, by;
    if (t < 1024) {
        int w = t >> 8, rem = t & 255;
        W  = (w == 0) ? Wq  : (w == 1) ? Wk  : (w == 2) ? Wv  : Wo;
        Wt = (w == 0) ? wqt : (w == 1) ? wkt : (w == 2) ? wvt : wot;
        K = 512; N = 512; bx = rem & 15; by = rem >> 4;
    } else if (t < 2048) {
        int rem = t - 1024;
        W = W1; Wt = w1t; K = 512; N = 2048; bx = rem & 63; by = rem >> 6;
    } else {
        int rem = t - 2048;
        W = W2; Wt = w2t; K = 2048; N = 512; bx = rem & 15; by = rem >> 4;
    }

    __shared__ float tile[32][33];
    int tx = threadIdx.x & 31, ty = threadIdx.x >> 5;
    #pragma unroll
    for (int r = ty; r < 32; r += 8)
        tile[r][tx] = W[(size_t)(by * 32 + r) * N + bx * 32 + tx];
    __syncthreads();
    #pragma unroll
    for (int r = ty; r < 32; r += 8)
        Wt[(size_t)(bx * 32 + r) * K + by * 32 + tx] = __float2bfloat16(tile[tx][r]);
}

// ---------------------------------------------------------------------------
// Kernel 2: x0[row,d] = emb[tokens[row], d]*sqrt(D) + PE(n,d); f32 + bf16 copy
// ---------------------------------------------------------------------------
__global__ __launch_bounds__(256) void embed_pe_kernel(
    const int* __restrict__ tokens, const float* __restrict__ emb,
    float* __restrict__ x, bf16* __restrict__ xb)
{
    int row = blockIdx.x;            // b*NSEQ + n
    int n   = row % NSEQ;
    int tok = tokens[row];
    const float sqrtD = 22.627416997969522f; // sqrt(512)
    for (int d = threadIdx.x; d < D_MODEL; d += 256) {
        float e = emb[tok * D_MODEL + d] * sqrtD;
        int   i2   = d & ~1;
        float expo = (float)i2 / (float)D_MODEL;
        float ang  = (float)n * powf(10000.0f, -expo);
        float pe   = (d & 1) ? cosf(ang) : sinf(ang);
        float val  = e + pe;
        x [(size_t)row * D_MODEL + d] = val;
        xb[(size_t)row * D_MODEL + d] = __float2bfloat16(val);
    }
}

// ---------------------------------------------------------------------------
// Kernel 3: fused QKV MFMA GEMM (no LDS). blockIdx.z selects q/k/v.
//  z=0: aexp = exp(2*(x@Wq+bq))   f32
//  z=1: bexp = exp(2*(x@Wk+bk))   f32
//  z=2: vT[b][d][j] = bf16(x@Wv+bv)   (transposed for PV MFMA B-operand)
// ---------------------------------------------------------------------------
__global__ __launch_bounds__(256) void qkv_mfma_kernel(
    const bf16* __restrict__ A,
    const bf16* __restrict__ wqt, const bf16* __restrict__ wkt, const bf16* __restrict__ wvt,
    const float* __restrict__ bq, const float* __restrict__ bk, const float* __restrict__ bv,
    float* __restrict__ aexp, float* __restrict__ bexp, bf16* __restrict__ vT)
{
    int z = blockIdx.z;
    const bf16*  Wt   = (z == 0) ? wqt : (z == 1) ? wkt : wvt;
    const float* bias = (z == 0) ? bq  : (z == 1) ? bk  : bv;

    int lane = threadIdx.x & 63, wid = threadIdx.x >> 6;
    int rowBase = blockIdx.y * 32 + (wid >> 1) * 16;
    int colBase = blockIdx.x * 64 + (wid & 1) * 32;

    const bf16* Ap  = A  + (size_t)(rowBase + (lane & 15)) * D_MODEL + ((lane >> 4) << 3);
    const bf16* Bp0 = Wt + (size_t)(colBase + (lane & 15)) * D_MODEL + ((lane >> 4) << 3);
    const bf16* Bp1 = Bp0 + (size_t)16 * D_MODEL;

    f32x4 acc0 = {0.f, 0.f, 0.f, 0.f};
    f32x4 acc1 = {0.f, 0.f, 0.f, 0.f};

    #pragma unroll 4
    for (int k0 = 0; k0 < D_MODEL; k0 += 32) {
        short8 a  = *reinterpret_cast<const short8*>(Ap  + k0);
        short8 b0 = *reinterpret_cast<const short8*>(Bp0 + k0);
        short8 b1 = *reinterpret_cast<const short8*>(Bp1 + k0);
        acc0 = __builtin_amdgcn_mfma_f32_16x16x32_bf16(a, b0, acc0, 0, 0, 0);
        acc1 = __builtin_amdgcn_mfma_f32_16x16x32_bf16(a, b1, acc1, 0, 0, 0);
    }

    int crow = rowBase + ((lane >> 4) << 2);   // rows crow..crow+3
    int ccol = colBase + (lane & 15);          // cols ccol, ccol+16

    if (z < 2) {
        float* C = (z == 0) ? aexp : bexp;
        #pragma unroll
        for (int r = 0; r < 4; ++r) {
            int row = crow + r;
            #pragma unroll
            for (int j = 0; j < 2; ++j) {
                int col = ccol + j * 16;
                float val = (j == 0 ? acc0[r] : acc1[r]) + bias[col];
                C[(size_t)row * D_MODEL + col] = __expf(2.0f * val);
            }
        }
    } else {
        int bb = crow / NSEQ;                  // batch (crow..crow+3 same batch)
        int jr = crow - bb * NSEQ;
        #pragma unroll
        for (int j = 0; j < 2; ++j) {
            int col = ccol + j * 16;
            short4v pk;
            #pragma unroll
            for (int r = 0; r < 4; ++r)
                pk[r] = bfb((j == 0 ? acc0[r] : acc1[r]) + bias[col]);
            size_t idx = ((size_t)bb * D_MODEL + col) * NSEQ + jr;
            *reinterpret_cast<short4v*>((short*)vT + idx) = pk;
        }
    }
}

// ---------------------------------------------------------------------------
// Kernel 4: additive-attention scores + softmax for TWO i-rows per block.
// u_j = sum_d (-2*scale_d) * rcp(a_id*b_jd + 1);  P = softmax_j(u)  (row
// constant sum(scale) cancels; |u|<=41 so no max-subtract needed).
// block = 512 thr (8 waves); wave w does j = w, w+8, ...; lane owns 8 d's.
// ---------------------------------------------------------------------------
__global__ __launch_bounds__(512) void score_softmax_kernel(
    const float* __restrict__ aexp, const float* __restrict__ bexp,
    const float* __restrict__ scale, bf16* __restrict__ P)
{
    int row0 = blockIdx.x * 2;
    int b    = row0 / NSEQ;
    int tid  = threadIdx.x;
    int lane = tid & 63, wid = tid >> 6;

    __shared__ float a0s[D_MODEL], a1s[D_MODEL], s2s[D_MODEL];
    __shared__ float sc[2][NSEQ];
    __shared__ float red[8];

    a0s[tid] = aexp[(size_t)row0 * D_MODEL + tid];
    a1s[tid] = aexp[(size_t)(row0 + 1) * D_MODEL + tid];
    s2s[tid] = -2.0f * scale[tid];
    __syncthreads();

    float a0[8], a1[8], sv[8];
    #pragma unroll
    for (int u = 0; u < 8; ++u) {
        a0[u] = a0s[lane * 8 + u];
        a1[u] = a1s[lane * 8 + u];
        sv[u] = s2s[lane * 8 + u];
    }

    const float* kb = bexp + (size_t)b * NSEQ * D_MODEL + lane * 8;
    for (int j = wid; j < NSEQ; j += 8) {
        const float4* kp = (const float4*)(kb + (size_t)j * D_MODEL);
        float4 b0 = kp[0], b1 = kp[1];
        float bb[8] = {b0.x, b0.y, b0.z, b0.w, b1.x, b1.y, b1.z, b1.w};
        float t0 = 0.0f, t1 = 0.0f;
        #pragma unroll
        for (int u = 0; u < 8; ++u) {
            float r0 = __builtin_amdgcn_rcpf(fmaf(a0[u], bb[u], 1.0f));
            float r1 = __builtin_amdgcn_rcpf(fmaf(a1[u], bb[u], 1.0f));
            t0 = fmaf(sv[u], r0, t0);
            t1 = fmaf(sv[u], r1, t1);
        }
        #pragma unroll
        for (int off = 32; off; off >>= 1) {
            t0 += __shfl_xor(t0, off, 64);
            t1 += __shfl_xor(t1, off, 64);
        }
        if (lane == 0) { sc[0][j] = t0; sc[1][j] = t1; }
    }
    __syncthreads();

    #pragma unroll
    for (int r = 0; r < 2; ++r) {
        float e = (tid < NSEQ) ? __expf(sc[r][tid]) : 0.0f;
        float s = e;
        #pragma unroll
        for (int off = 32; off; off >>= 1) s += __shfl_xor(s, off, 64);
        if (lane == 0) red[wid] = s;
        __syncthreads();
        if (tid == 0) {
            float t = 0.0f;
            #pragma unroll
            for (int w = 0; w < 8; ++w) t += red[w];
            red[0] = t;
        }
        __syncthreads();
        float inv = 1.0f / red[0];
        if (tid < NSEQ)
            P[(size_t)(row0 + r) * NSEQ + tid] = __float2bfloat16(e * inv);
        __syncthreads();
    }
}

// ---------------------------------------------------------------------------
// Kernel 5: PV MFMA:  attnb[b,i,d] = sum_j P[b,i,j] * v[b,j,d]
// A = P (bf16 [384][384] per batch), B = vT (bf16 [512][384] per batch)
// grid (D/64, 384/32, 2); 256 thr.
// ---------------------------------------------------------------------------
__global__ __launch_bounds__(256) void pv_mfma_kernel(
    const bf16* __restrict__ P, const bf16* __restrict__ vT,
    bf16* __restrict__ attnb)
{
    int z = blockIdx.z;
    int lane = threadIdx.x & 63, wid = threadIdx.x >> 6;
    int rowBase = blockIdx.y * 32 + (wid >> 1) * 16;
    int colBase = blockIdx.x * 64 + (wid & 1) * 32;

    const bf16* Ap  = P  + ((size_t)z * NSEQ + rowBase + (lane & 15)) * NSEQ + ((lane >> 4) << 3);
    const bf16* Bp0 = vT + ((size_t)z * D_MODEL + colBase + (lane & 15)) * NSEQ + ((lane >> 4) << 3);
    const bf16* Bp1 = Bp0 + (size_t)16 * NSEQ;

    f32x4 acc0 = {0.f, 0.f, 0.f, 0.f};
    f32x4 acc1 = {0.f, 0.f, 0.f, 0.f};

    #pragma unroll 4
    for (int k0 = 0; k0 < NSEQ; k0 += 32) {
        short8 a  = *reinterpret_cast<const short8*>(Ap  + k0);
        short8 b0 = *reinterpret_cast<const short8*>(Bp0 + k0);
        short8 b1 = *reinterpret_cast<const short8*>(Bp1 + k0);
        acc0 = __builtin_amdgcn_mfma_f32_16x16x32_bf16(a, b0, acc0, 0, 0, 0);
        acc1 = __builtin_amdgcn_mfma_f32_16x16x32_bf16(a, b1, acc1, 0, 0, 0);
    }

    int crow = rowBase + ((lane >> 4) << 2);
    int ccol = colBase + (lane & 15);
    #pragma unroll
    for (int r = 0; r < 4; ++r)
        #pragma unroll
        for (int j = 0; j < 2; ++j)
            attnb[((size_t)z * NSEQ + crow + r) * D_MODEL + ccol + j * 16] =
                __float2bfloat16(j == 0 ? acc0[r] : acc1[r]);
}

// ---------------------------------------------------------------------------
// Kernel 6: generic bf16 MFMA GEMM (no LDS): C = A @ Wt^T + bias (+resid)(+relu)
// ---------------------------------------------------------------------------
__global__ __launch_bounds__(256) void mfma_gemm_kernel(
    const bf16* __restrict__ A, const bf16* __restrict__ Wt,
    const float* __restrict__ bias, const float* __restrict__ resid,
    float* __restrict__ Cf, bf16* __restrict__ Cb,
    int K, int N, int relu)
{
    int lane = threadIdx.x & 63, wid = threadIdx.x >> 6;
    int rowBase = blockIdx.y * 32 + (wid >> 1) * 16;
    int colBase = blockIdx.x * 64 + (wid & 1) * 32;

    const bf16* Ap  = A  + (size_t)(rowBase + (lane & 15)) * K + ((lane >> 4) << 3);
    const bf16* Bp0 = Wt + (size_t)(colBase + (lane & 15)) * K + ((lane >> 4) << 3);
    const bf16* Bp1 = Bp0 + (size_t)16 * K;

    f32x4 acc0 = {0.f, 0.f, 0.f, 0.f};
    f32x4 acc1 = {0.f, 0.f, 0.f, 0.f};

    #pragma unroll 4
    for (int k0 = 0; k0 < K; k0 += 32) {
        short8 a  = *reinterpret_cast<const short8*>(Ap  + k0);
        short8 b0 = *reinterpret_cast<const short8*>(Bp0 + k0);
        short8 b1 = *reinterpret_cast<const short8*>(Bp1 + k0);
        acc0 = __builtin_amdgcn_mfma_f32_16x16x32_bf16(a, b0, acc0, 0, 0, 0);
        acc1 = __builtin_amdgcn_mfma_f32_16x16x32_bf16(a, b1, acc1, 0, 0, 0);
    }

    int crow = rowBase + ((lane >> 4) << 2);
    int ccol = colBase + (lane & 15);
    #pragma unroll
    for (int r = 0; r < 4; ++r) {
        int row = crow + r;
        #pragma unroll
        for (int j = 0; j < 2; ++j) {
            int col = ccol + j * 16;
            float val = (j == 0 ? acc0[r] : acc1[r]) + bias[col];
            if (resid) val += resid[(size_t)row * N + col];
            if (relu)  val = fmaxf(val, 0.0f);
            if (Cf) Cf[(size_t)row * N + col] = val;
            if (Cb) Cb[(size_t)row * N + col] = __float2bfloat16(val);
        }
    }
}

// ---------------------------------------------------------------------------
// Kernel 7: LayerNorm over last dim (512); optional bf16 shadow output
// ---------------------------------------------------------------------------
__global__ __launch_bounds__(256) void ln_kernel(
    const float* __restrict__ in, const float* __restrict__ gamma,
    const float* __restrict__ beta, float* __restrict__ out,
    bf16* __restrict__ outb)
{
    int row = blockIdx.x;
    int tid = threadIdx.x;
    int lane = tid & 63, wid = tid >> 6;
    __shared__ float red[4];

    float v0 = in[(size_t)row * D_MODEL + tid];
    float v1 = in[(size_t)row * D_MODEL + tid + 256];

    float s = v0 + v1;
    #pragma unroll
    for (int off = 32; off; off >>= 1) s += __shfl_xor(s, off, 64);
    if (lane == 0) red[wid] = s;
    __syncthreads();
    if (tid == 0) red[0] = red[0] + red[1] + red[2] + red[3];
    __syncthreads();
    float mu = red[0] * (1.0f / D_MODEL);
    __syncthreads();

    float d0 = v0 - mu, d1 = v1 - mu;
    float s2 = d0 * d0 + d1 * d1;
    #pragma unroll
    for (int off = 32; off; off >>= 1) s2 += __shfl_xor(s2, off, 64);
    if (lane == 0) red[wid] = s2;
    __syncthreads();
    if (tid == 0) red[0] = red[0] + red[1] + red[2] + red[3];
    __syncthreads();
    float var = red[0] * (1.0f / D_MODEL);
    float inv = rsqrtf(var + LN_EPS);

    float o0 = d0 * inv * gamma[tid] + beta[tid];
    float o1 = d1 * inv * gamma[tid + 256] + beta[tid + 256];
    out[(size_t)row * D_MODEL + tid]       = o0;
    out[(size_t)row * D_MODEL + tid + 256] = o1;
    if (outb) {
        outb[(size_t)row * D_MODEL + tid]       = __float2bfloat16(o0);
        outb[(size_t)row * D_MODEL + tid + 256] = __float2bfloat16(o1);
    }
}

// ---------------------------------------------------------------------------
extern "C" void kernel_launch(void* const* d_in, const int* in_sizes, int n_in,
                              void* d_out, int out_size, void* d_ws, size_t ws_size,
                              hipStream_t stream)
{
    const int*   tokens = (const int*)  d_in[0];
    const float* emb    = (const float*)d_in[1];
    const float* Wq     = (const float*)d_in[2];
    const float* bq     = (const float*)d_in[3];
    const float* Wk     = (const float*)d_in[4];
    const float* bk     = (const float*)d_in[5];
    const float* Wv     = (const float*)d_in[6];
    const float* bv     = (const float*)d_in[7];
    const float* ascale = (const float*)d_in[8];
    const float* Wo     = (const float*)d_in[9];
    const float* bo     = (const float*)d_in[10];
    const float* g1     = (const float*)d_in[11];
    const float* beta1  = (const float*)d_in[12];
    const float* W1     = (const float*)d_in[13];
    const float* bf1    = (const float*)d_in[14];
    const float* W2     = (const float*)d_in[15];
    const float* bf2    = (const float*)d_in[16];
    const float* g2     = (const float*)d_in[17];
    const float* beta2  = (const float*)d_in[18];

    float* out = (float*)d_out;
    float* ws  = (float*)d_ws;

    const size_t SZ = (size_t)NROWS * D_MODEL;   // 393216

    float* x0   = ws;            // live until Wo residual
    float* aexp = ws + 1 * SZ;   // exp(2q); dead after score -> reuse as t1
    float* bexp = ws + 2 * SZ;   // exp(2k); dead after score -> reuse as x1
    float* t1 = aexp;
    float* x1 = bexp;
    float* y  = x0;              // x0 dead after Wo

    bf16* x0b   = (bf16*)(ws + 3 * SZ);
    bf16* attnb = x0b + SZ;
    bf16* x1b   = attnb + SZ;
    bf16* hb    = x1b + SZ;                          // NROWS * D_FF
    bf16* Pb    = hb + (size_t)NROWS * D_FF;         // 2*384*384
    bf16* vTb   = Pb + (size_t)NBATCH * NSEQ * NSEQ; // 2*512*384
    bf16* wqt   = vTb + (size_t)NBATCH * D_MODEL * NSEQ;
    bf16* wkt   = wqt + (size_t)D_MODEL * D_MODEL;
    bf16* wvt   = wkt + (size_t)D_MODEL * D_MODEL;
    bf16* wot   = wvt + (size_t)D_MODEL * D_MODEL;
    bf16* w1t   = wot + (size_t)D_MODEL * D_MODEL;   // [D_FF][D_MODEL]
    bf16* w2t   = w1t + (size_t)D_MODEL * D_FF;      // [D_MODEL][D_FF]

    // 1. all weight transposes (one dispatch)
    wt_all_kernel<<<3072, 256, 0, stream>>>(Wq, Wk, Wv, Wo, W1, W2,
                                            wqt, wkt, wvt, wot, w1t, w2t);

    // 2. embedding + positional encoding
    embed_pe_kernel<<<NROWS, 256, 0, stream>>>(tokens, emb, x0, x0b);

    // 3. fused QKV (z: 0->aexp, 1->bexp, 2->vT bf16)
    qkv_mfma_kernel<<<dim3(D_MODEL / 64, NROWS / 32, 3), 256, 0, stream>>>(
        x0b, wqt, wkt, wvt, bq, bk, bv, aexp, bexp, vTb);

    // 4. scores + softmax -> P bf16
    score_softmax_kernel<<<NROWS / 2, 512, 0, stream>>>(aexp, bexp, ascale, Pb);

    // 5. PV -> attnb bf16
    pv_mfma_kernel<<<dim3(D_MODEL / 64, NSEQ / 32, NBATCH), 256, 0, stream>>>(
        Pb, vTb, attnb);

    // 6. output projection + residual -> t1 f32
    mfma_gemm_kernel<<<dim3(D_MODEL / 64, NROWS / 32), 256, 0, stream>>>(
        attnb, wot, bo, x0, t1, nullptr, D_MODEL, D_MODEL, 0);

    // 7. LayerNorm 1 -> x1 f32 + x1b bf16
    ln_kernel<<<NROWS, 256, 0, stream>>>(t1, g1, beta1, x1, x1b);

    // 8. FF up + ReLU -> hb bf16
    mfma_gemm_kernel<<<dim3(D_FF / 64, NROWS / 32), 256, 0, stream>>>(
        x1b, w1t, bf1, nullptr, nullptr, hb, D_MODEL, D_FF, 1);

    // 9. FF down + residual -> y f32
    mfma_gemm_kernel<<<dim3(D_MODEL / 64, NROWS / 32), 256, 0, stream>>>(
        hb, w2t, bf2, x1, y, nullptr, D_FF, D_MODEL, 0);

    // 10. LayerNorm 2 -> out
    ln_kernel<<<NROWS, 256, 0, stream>>>(y, g2, beta2, out, nullptr);
}